// Round 10
// baseline (230.238 us; speedup 1.0000x reference)
//
#include <hip/hip_runtime.h>
#include <cstdint>

#define DIMN 1024
#define SEQ  2048
#define BATCH 2
#define MTOT (BATCH*SEQ)      // 4096 rows
#define NELEM_ACT (MTOT*DIMN) // 4,194,304
#define NELEM_W   (DIMN*DIMN) // 1,048,576

typedef __attribute__((ext_vector_type(8))) short   s16x8;
typedef __attribute__((ext_vector_type(4))) float   f32x4v;

__device__ __forceinline__ float b2f(unsigned short u) {
  union { unsigned int i; float f; } x; x.i = ((unsigned int)u) << 16; return x.f;
}
__device__ __forceinline__ unsigned short f2b(float f) {
  unsigned int x = __float_as_uint(f);
  return (unsigned short)((x + 0x7fffu + ((x >> 16) & 1u)) >> 16);
}

__device__ __forceinline__ void gload16(const void* g, void* l) {
  __builtin_amdgcn_global_load_lds((const __attribute__((address_space(1))) void*)g,
                                   (__attribute__((address_space(3))) void*)l,
                                   16, 0, 0);
}

// counted vmcnt wait, literal immediates (T4)
template<int N> __device__ __forceinline__ void waitvm() {
  if constexpr (N == 0)       asm volatile("s_waitcnt vmcnt(0)" ::: "memory");
  else if constexpr (N == 3)  asm volatile("s_waitcnt vmcnt(3)" ::: "memory");
  else if constexpr (N == 4)  asm volatile("s_waitcnt vmcnt(4)" ::: "memory");
  else if constexpr (N == 6)  asm volatile("s_waitcnt vmcnt(6)" ::: "memory");
  else if constexpr (N == 8)  asm volatile("s_waitcnt vmcnt(8)" ::: "memory");
  else static_assert(N == 0, "add a case");
}

// ---------------------------------------------------------------------------
// fp32 -> bf16 (elementwise, 8 elems/thread)
// ---------------------------------------------------------------------------
__global__ __launch_bounds__(256) void cvt_kernel(
    const float* __restrict__ in, unsigned short* __restrict__ out, int n) {
  int i = (blockIdx.x * 256 + threadIdx.x) * 8;
  if (i >= n) return;
  float4 v0 = *(const float4*)(in + i);
  float4 v1 = *(const float4*)(in + i + 4);
  ushort4 a, b;
  a.x = f2b(v0.x); a.y = f2b(v0.y); a.z = f2b(v0.z); a.w = f2b(v0.w);
  b.x = f2b(v1.x); b.y = f2b(v1.y); b.z = f2b(v1.z); b.w = f2b(v1.w);
  *(ushort4*)(out + i) = a;
  *(ushort4*)(out + i + 4) = b;
}

// ---------------------------------------------------------------------------
// All 5 weight transposes in one dispatch; z selects the weight.
// ---------------------------------------------------------------------------
__global__ __launch_bounds__(256) void transpose5_kernel(
    const float* __restrict__ w1, const float* __restrict__ w2,
    const float* __restrict__ qw, const float* __restrict__ kw,
    const float* __restrict__ vw,
    unsigned short* __restrict__ w1t, unsigned short* __restrict__ w2t,
    unsigned short* __restrict__ wqkvt) {
  __shared__ float t[32][33];
  int z = blockIdx.z;
  const float* in = (z == 0) ? w1 : (z == 1) ? w2 : (z == 2) ? qw : (z == 3) ? kw : vw;
  unsigned short* dst = (z == 0) ? w1t : (z == 1) ? w2t : wqkvt + (size_t)(z - 2) * NELEM_W;

  int tx = threadIdx.x & 31, ty = threadIdx.x >> 5;  // 32 x 8
  int r0 = blockIdx.y * 32, c0 = blockIdx.x * 32;
  #pragma unroll
  for (int i = 0; i < 32; i += 8)
    t[ty + i][tx] = in[(size_t)(r0 + ty + i) * DIMN + c0 + tx];
  __syncthreads();
  #pragma unroll
  for (int i = 0; i < 32; i += 8)
    dst[(size_t)(c0 + ty + i) * DIMN + r0 + tx] = f2b(t[tx][ty + i]);
}

// ---------------------------------------------------------------------------
// GEMM: C[M,N] = A[M,K] @ Bt[N,K]^T + bias   (bf16 in, f32 accum)
// Block tile (MF*32) x (NF*32), BK=32, 256 threads = 4 waves as 2x2.
// RING-3 LOOKAHEAD-2.5 (r9 post-mortem): 3 static LDS buffers (48KB QKV /
//   36KB MLP) -> 3 blocks/CU co-residency (vs ring-4's 64KB capping at 2).
//   Per step s: waitvm(min(2,nt-1-s)*NL) -> raw barrier -> sched_barrier ->
//   compute(buf s%3) -> barrier -> stage(buf s%3, s+3).
//   Counted vmcnt keeps 2 tiles in flight across barriers (T4, m218);
//   cross-block wave overlap (m114) fills the remaining latency.
// No XCD swizzle (r8: contiguous-chunk swizzle thrashed B in per-XCD L2).
// Fragment-major LDS (1KB 16x32 blocks): gload16 + ds_read_b128 conflict-free.
// EPI 0: relu+bf16.  EPI 1: bf16.
// EPI 2 (fused QKV, N=3072): cols 0..2047 -> qk[token][2048] (q|k);
//        cols 2048.. -> VT[d][token] transposed write, bias per group.
// ---------------------------------------------------------------------------
template<int MF, int NF, int EPI>
__global__ __launch_bounds__(256) void gemm_kernel(
    const unsigned short* __restrict__ A, const unsigned short* __restrict__ Bt,
    const float* __restrict__ bias0, const float* __restrict__ bias1,
    const float* __restrict__ bias2,
    unsigned short* __restrict__ O, unsigned short* __restrict__ O2,
    int Ndim, int Kdim) {
  constexpr int TB = (MF + NF) * 2;              // 1KB blocks per buffer (BK=32)
  constexpr int NL = TB / 4;                     // per-thread loads per stage
  __shared__ unsigned short lds[3 * TB * 512];

  const int tid  = threadIdx.x;
  const int lane = tid & 63;
  const int wave = tid >> 6;
  const int wm = wave >> 1;
  const int wn = wave & 1;
  const int frow = lane & 15;
  const int krow = lane >> 4;
  const int bm0 = blockIdx.y * (MF * 32);
  const int bn0 = blockIdx.x * (NF * 32);

  f32x4v acc[MF][NF] = {};

  auto stage = [&](unsigned short* dst, int k0) {
    #pragma unroll
    for (int t = 0; t < NL; ++t) {
      int i = wave + t * 4;
      const unsigned short* src;
      if (i < MF * 2) {
        src = A + (size_t)(bm0 + i * 16 + frow) * Kdim + k0 + krow * 8;
      } else {
        int j = i - MF * 2;
        src = Bt + (size_t)(bn0 + j * 16 + frow) * Kdim + k0 + krow * 8;
      }
      gload16(src, dst + i * 512);
    }
  };

  auto compute = [&](const unsigned short* buf) {
    const short* sl = (const short*)buf;
    s16x8 a[MF], b[NF];
    #pragma unroll
    for (int m = 0; m < MF; ++m)
      a[m] = *(const s16x8*)(sl + (wm * MF + m) * 512 + lane * 8);
    #pragma unroll
    for (int n = 0; n < NF; ++n)
      b[n] = *(const s16x8*)(sl + (MF * 2 + wn * NF + n) * 512 + lane * 8);
    #pragma unroll
    for (int m = 0; m < MF; ++m)
      #pragma unroll
      for (int n = 0; n < NF; ++n)
        acc[m][n] = __builtin_amdgcn_mfma_f32_16x16x32_bf16(a[m], b[n], acc[m][n], 0, 0, 0);
  };

  const int nt = Kdim >> 5;        // BK=32 steps (Kdim=1024 -> 32)
  unsigned short* b0 = lds;
  unsigned short* b1 = lds + TB * 512;
  unsigned short* b2 = lds + 2 * TB * 512;

  stage(b0, 0); stage(b1, 32); stage(b2, 64);

  #define PHASE(S, BUF)                                                       \
  {                                                                           \
    int s_ = (S);                                                             \
    int rem = nt - 1 - s_;         /* uniform */                              \
    if (rem >= 2)      waitvm<2 * NL>();                                      \
    else if (rem == 1) waitvm<NL>();                                          \
    else               waitvm<0>();                                           \
    __builtin_amdgcn_s_barrier();                                             \
    __builtin_amdgcn_sched_barrier(0);                                        \
    compute(BUF);                                                             \
    __builtin_amdgcn_s_barrier();                                             \
    if (s_ + 3 < nt) stage(BUF, (s_ + 3) << 5);                               \
  }
  int t = 0;
  for (; t + 3 <= nt; t += 3) {
    PHASE(t,     b0)
    PHASE(t + 1, b1)
    PHASE(t + 2, b2)
  }
  if (t < nt)     PHASE(t, b0)
  if (t + 1 < nt) PHASE(t + 1, b1)
  #undef PHASE

  // epilogue: frag C row = (lane>>4)*4 + r, col = lane&15
  #pragma unroll
  for (int n = 0; n < NF; ++n) {
    int col = bn0 + wn * (NF * 16) + n * 16 + frow;
    float bv;
    if (EPI == 2) {
      int sel = col >> 10;
      const float* bp = (sel == 0) ? bias0 : (sel == 1) ? bias1 : bias2;
      bv = bp[col & (DIMN - 1)];
    } else {
      bv = bias0[col];
    }
    #pragma unroll
    for (int m = 0; m < MF; ++m) {
      int rbase = bm0 + wm * (MF * 16) + m * 16 + krow * 4;
      if (EPI == 2 && col >= 2048) {
        // transposed V write: VT[d][token], 4 consecutive tokens -> 8B store
        int d = col - 2048;
        ushort4 pk;
        pk.x = f2b(acc[m][n][0] + bv); pk.y = f2b(acc[m][n][1] + bv);
        pk.z = f2b(acc[m][n][2] + bv); pk.w = f2b(acc[m][n][3] + bv);
        *(ushort4*)(O2 + (size_t)d * MTOT + rbase) = pk;
      } else {
        #pragma unroll
        for (int r = 0; r < 4; ++r) {
          float v = acc[m][n][r] + bv;
          if (EPI == 0) v = fmaxf(v, 0.f);
          if (EPI == 2) O[(size_t)(rbase + r) * 2048 + col] = f2b(v);
          else          O[(size_t)(rbase + r) * Ndim + col] = f2b(v);
        }
      }
    }
  }
}

// ---------------------------------------------------------------------------
// MFMA sliding-window attention.  One block per 32 queries (grid 128).
// Padded key window: 96 keys [s0-32, s0+63].  4 waves: qf = w&1 (16 q rows),
// kh = w>>1 (key half for QK / d half for PV).
// S^T = K @ Q^T so softmax is lane-local per q (4-lane shfl groups) with a
// 2-half LDS combine.  P -> bf16 in padded LDS.  PV uses VT[d][token].
// (unchanged for attribution)
// ---------------------------------------------------------------------------
#define QBLK 32
#define NEGI (-1.0e30f)

__global__ __launch_bounds__(256) void attn_mfma_kernel(
    const unsigned short* __restrict__ qk,   // [MTOT][2048]  (q|k)
    const unsigned short* __restrict__ vt,   // [DIMN][MTOT]
    float* __restrict__ out) {               // [MTOT][DIMN]
  __shared__ unsigned short stage[24 * 512];   // 24 KB
  __shared__ unsigned short plds[QBLK][136];   // P bf16, padded
  __shared__ float pmax[2][QBLK];
  __shared__ float psum[2][QBLK];

  const int tid = threadIdx.x, lane = tid & 63, wave = tid >> 6;
  const int frow = lane & 15, krow = lane >> 4;
  const int tok0 = blockIdx.x * QBLK;
  const int s0 = tok0 & (SEQ - 1);
  const int bbase = tok0 - s0;
  const int qf = wave & 1;
  const int kh = wave >> 1;

  // ---------------- QK^T ----------------
  f32x4v sacc[3] = {};
  for (int d0 = 0; d0 < DIMN; d0 += 64) {
    #pragma unroll
    for (int t = 0; t < 4; ++t) {
      int i = wave + t * 4;
      const unsigned short* src;
      if (i < 4) {
        int qfs = i >> 1, ds = i & 1;
        src = qk + (size_t)(tok0 + qfs * 16 + frow) * 2048 + d0 + ds * 32 + krow * 8;
      } else {
        int j = i - 4;
        int kf = j >> 1, ds = j & 1;
        int kpos = s0 - 32 + kf * 16 + frow;
        kpos = min(max(kpos, 0), SEQ - 1);
        src = qk + (size_t)(bbase + kpos) * 2048 + 1024 + d0 + ds * 32 + krow * 8;
      }
      gload16(src, stage + i * 512);
    }
    __syncthreads();
    const short* sl = (const short*)stage;
    #pragma unroll
    for (int ds = 0; ds < 2; ++ds) {
      s16x8 bq = *(const s16x8*)(sl + (qf * 2 + ds) * 512 + lane * 8);
      #pragma unroll
      for (int f = 0; f < 3; ++f) {
        int kf = kh * 3 + f;
        s16x8 ak = *(const s16x8*)(sl + (4 + kf * 2 + ds) * 512 + lane * 8);
        sacc[f] = __builtin_amdgcn_mfma_f32_16x16x32_bf16(ak, bq, sacc[f], 0, 0, 0);
      }
    }
    __syncthreads();
  }

  // ---------------- mask + softmax ----------------
  const int qloc = qf * 16 + frow;
  const int qpos = s0 + qloc;
  float sv[3][4];
  float mx = NEGI;
  #pragma unroll
  for (int f = 0; f < 3; ++f) {
    #pragma unroll
    for (int r = 0; r < 4; ++r) {
      int kloc = (kh * 3 + f) * 16 + krow * 4 + r;
      int kpos = s0 - 32 + kloc;
      int dd = kpos - qpos;
      bool valid = (dd >= -32) && (dd <= 32) && (kpos >= 0) && (kpos < SEQ);
      float v = valid ? sacc[f][r] * 0.03125f : NEGI;
      sv[f][r] = v;
      mx = fmaxf(mx, v);
    }
  }
  mx = fmaxf(mx, __shfl_xor(mx, 16));
  mx = fmaxf(mx, __shfl_xor(mx, 32));
  if (lane < 16) pmax[kh][qf * 16 + lane] = mx;
  __syncthreads();
  float M = fmaxf(pmax[0][qloc], pmax[1][qloc]);
  float sum = 0.f;
  unsigned int pw[3][2];
  #pragma unroll
  for (int f = 0; f < 3; ++f) {
    #pragma unroll
    for (int pr = 0; pr < 2; ++pr) {
      float p0 = __expf(sv[f][2 * pr]     - M);
      float p1 = __expf(sv[f][2 * pr + 1] - M);
      sum += p0 + p1;
      pw[f][pr] = (unsigned int)f2b(p0) | ((unsigned int)f2b(p1) << 16);
    }
  }
  sum += __shfl_xor(sum, 16);
  sum += __shfl_xor(sum, 32);
  if (lane < 16) psum[kh][qf * 16 + lane] = sum;
  {
    unsigned int* pl = (unsigned int*)&plds[0][0];
    int base = qloc * 68 + (kh * 3) * 8 + krow * 2;
    #pragma unroll
    for (int f = 0; f < 3; ++f) {
      pl[base + f * 8 + 0] = pw[f][0];
      pl[base + f * 8 + 1] = pw[f][1];
    }
  }
  __syncthreads();

  // ---------------- PV ----------------
  s16x8 pa[3];
  #pragma unroll
  for (int kf = 0; kf < 3; ++kf)
    pa[kf] = *(const s16x8*)((const short*)&plds[0][0] +
                             (qf * 16 + frow) * 136 + kf * 32 + krow * 8);
  float rden[4];
  #pragma unroll
  for (int r = 0; r < 4; ++r) {
    int q = qf * 16 + krow * 4 + r;
    rden[r] = 1.f / (psum[0][q] + psum[1][q]);
  }

  for (int c = 0; c < 8; ++c) {           // d-chunks of 128
    #pragma unroll
    for (int t = 0; t < 6; ++t) {
      int i = wave + t * 4;
      int kf = i >> 3, nf = i & 7;
      int d = c * 128 + nf * 16 + frow;
      int tt = s0 - 32 + kf * 32 + krow * 8;
      tt = min(max(tt, 0), SEQ - 8);      // 8-token groups never straddle
      gload16(vt + (size_t)d * MTOT + bbase + tt, stage + i * 512);
    }
    __syncthreads();
    const short* sl = (const short*)stage;
    f32x4v oacc[4] = {};
    #pragma unroll
    for (int kf = 0; kf < 3; ++kf) {
      #pragma unroll
      for (int n = 0; n < 4; ++n) {
        int nf = kh * 4 + n;
        s16x8 bv = *(const s16x8*)(sl + (kf * 8 + nf) * 512 + lane * 8);
        oacc[n] = __builtin_amdgcn_mfma_f32_16x16x32_bf16(pa[kf], bv, oacc[n], 0, 0, 0);
      }
    }
    #pragma unroll
    for (int n = 0; n < 4; ++n) {
      int d = c * 128 + (kh * 4 + n) * 16 + frow;
      #pragma unroll
      for (int r = 0; r < 4; ++r) {
        int q = qf * 16 + krow * 4 + r;
        out[(size_t)(tok0 + q) * DIMN + d] = oacc[n][r] * rden[r];
      }
    }
    __syncthreads();
  }
}

// ---------------------------------------------------------------------------
extern "C" void kernel_launch(void* const* d_in, const int* in_sizes, int n_in,
                              void* d_out, int out_size, void* d_ws, size_t ws_size,
                              hipStream_t stream) {
  const float* x  = (const float*)d_in[0];
  const float* w1 = (const float*)d_in[1];
  const float* b1 = (const float*)d_in[2];
  const float* w2 = (const float*)d_in[3];
  const float* b2 = (const float*)d_in[4];
  const float* qw = (const float*)d_in[5];
  const float* qb = (const float*)d_in[6];
  const float* kw = (const float*)d_in[7];
  const float* kb = (const float*)d_in[8];
  const float* vw = (const float*)d_in[9];
  const float* vb = (const float*)d_in[10];
  float* out = (float*)d_out;

  char* ws = (char*)d_ws;
  const size_t MB = 1024 * 1024;
  unsigned short* x_bf  = (unsigned short*)(ws);             // 8 MB
  unsigned short* h_bf  = (unsigned short*)(ws + 8  * MB);   // 8 MB
  unsigned short* m_bf  = (unsigned short*)(ws + 16 * MB);   // 8 MB
  unsigned short* qkbuf = (unsigned short*)(ws + 24 * MB);   // 16 MB [4096][2048]
  unsigned short* vtbuf = (unsigned short*)(ws + 40 * MB);   // 8 MB  [1024][4096]
  unsigned short* w1t   = (unsigned short*)(ws + 48 * MB);   // 2 MB
  unsigned short* w2t   = (unsigned short*)(ws + 50 * MB);   // 2 MB
  unsigned short* wqkvt = (unsigned short*)(ws + 52 * MB);   // 6 MB

  cvt_kernel<<<NELEM_ACT / (256 * 8), 256, 0, stream>>>(x, x_bf, NELEM_ACT);
  transpose5_kernel<<<dim3(32, 32, 5), 256, 0, stream>>>(w1, w2, qw, kw, vw,
                                                         w1t, w2t, wqkvt);

  // MLP GEMMs: 64x128 tile -> 512 blocks, 3x12KB LDS ring, NL=3
  dim3 g1(DIMN / 128, MTOT / 64);
  gemm_kernel<2, 4, 0><<<g1, 256, 0, stream>>>(x_bf, w1t, b1, nullptr, nullptr,
                                               h_bf, nullptr, DIMN, DIMN);
  gemm_kernel<2, 4, 1><<<g1, 256, 0, stream>>>(h_bf, w2t, b2, nullptr, nullptr,
                                               m_bf, nullptr, DIMN, DIMN);
  // fused QKV GEMM: 128x128 tile over N=3072 -> 768 blocks, 3x16KB ring, NL=4
  dim3 g2(3 * DIMN / 128, MTOT / 128);
  gemm_kernel<4, 4, 2><<<g2, 256, 0, stream>>>(m_bf, wqkvt, qb, kb, vb,
                                               qkbuf, vtbuf, 3 * DIMN, DIMN);

  attn_mfma_kernel<<<MTOT / QBLK, 256, 0, stream>>>(qkbuf, vtbuf, out);
}